// Round 8
// baseline (410.344 us; speedup 1.0000x reference)
//
#include <hip/hip_runtime.h>
#include <hip/hip_bf16.h>

typedef unsigned short u16;
typedef unsigned int u32;
typedef __bf16 bf16x8 __attribute__((ext_vector_type(8)));
typedef float f32x4 __attribute__((ext_vector_type(4)));
typedef u32 u32x2 __attribute__((ext_vector_type(2)));

#define AS1 __attribute__((address_space(1)))
#define AS3 __attribute__((address_space(3)))

__device__ __forceinline__ void gload16(const void* gp, void* lp) {
    __builtin_amdgcn_global_load_lds((const AS1 u32*)gp, (AS3 u32*)lp, 16, 0, 0);
}

__device__ __forceinline__ u16 f2b(float f) {
    __bf16 h = (__bf16)f;
    return __builtin_bit_cast(u16, h);
}

// ---------------- fused prep: x->bf16 convert + 4 weight transposes ----------------
// blocks 0..8191: cvt; 8192..12287: wq^T; 12288..13311: wk^T; 13312..14335: wv^T; 14336..18431: wo^T
__global__ __launch_bounds__(256) void prep_kernel(const float* __restrict__ x,
                                                   const float* __restrict__ wq,
                                                   const float* __restrict__ wk,
                                                   const float* __restrict__ wv,
                                                   const float* __restrict__ wo,
                                                   u16* __restrict__ xb,
                                                   u16* __restrict__ wT,
                                                   u16* __restrict__ woT) {
    __shared__ u16 tile[32][33];
    const int bid = blockIdx.x, tid = threadIdx.x;
    if (bid < 8192) {
        int i = bid * 256 + tid;
        f32x4 v = *(const f32x4*)(x + (size_t)i * 4);
        u32x2 o;
        o[0] = (u32)f2b(v[0]) | ((u32)f2b(v[1]) << 16);
        o[1] = (u32)f2b(v[2]) | ((u32)f2b(v[3]) << 16);
        *(u32x2*)(xb + (size_t)i * 4) = o;
        return;
    }
    const float* in;
    u16* out;
    int C, t;
    if (bid < 12288) { t = bid - 8192; in = wq; out = wT; C = 2048; }
    else if (bid < 13312) { t = bid - 12288; in = wk; out = wT + 2048 * 2048; C = 512; }
    else if (bid < 14336) { t = bid - 13312; in = wv; out = wT + 2560 * 2048; C = 512; }
    else { t = bid - 14336; in = wo; out = woT; C = 2048; }
    const int nbx = C >> 5;
    const int bx = (t % nbx) * 32, by = (t / nbx) * 32;
    const int tx = tid & 31, ty = tid >> 5;
#pragma unroll
    for (int i = 0; i < 32; i += 8)
        tile[ty + i][tx] = f2b(in[(size_t)(by + ty + i) * C + bx + tx]);
    __syncthreads();
#pragma unroll
    for (int i = 0; i < 32; i += 8)
        out[(size_t)(bx + ty + i) * 2048 + by + tx] = tile[tx][ty + i];
}

// ---------------- transpose V section of qkv -> vT[b][kvh][d][s] ----------------
__global__ __launch_bounds__(256) void transpose_v(const u16* __restrict__ qkv,
                                                   u16* __restrict__ vT) {
    __shared__ u16 tile[32][33];
    const int bx = blockIdx.x * 32;  // c in 0..511 (= kvh*128+d)
    const int by = blockIdx.y * 32;  // row in 0..4095 (= b*2048+s)
    const int tx = threadIdx.x & 31, ty = threadIdx.x >> 5;
#pragma unroll
    for (int i = 0; i < 32; i += 8)
        tile[ty + i][tx] = qkv[(size_t)(by + ty + i) * 3072 + 2560 + bx + tx];
    __syncthreads();
    const int b = by >> 11, s0 = by & 2047;
#pragma unroll
    for (int i = 0; i < 32; i += 8)
        vT[(size_t)(b * 512 + bx + ty + i) * 2048 + s0 + tx] = tile[tx][ty + i];
}

// ---------------- GEMM: C[M][ldc slice] = A[M][K] * Bt[N][K]^T, bf16 in, OT out ----------------
// m97 structure + XCD swizzle; optional fused RoPE epilogue (for the qkv projection).
template <typename OT, bool ROPE>
__global__ __launch_bounds__(256) void gemm_bt(const __bf16* __restrict__ A,
                                               const __bf16* __restrict__ Bt,
                                               OT* __restrict__ C,
                                               int K, int ldc,
                                               const float* __restrict__ fc,
                                               const float* __restrict__ fs) {
    __shared__ __align__(16) __bf16 Al[128 * 32];
    __shared__ __align__(16) __bf16 Bl[128 * 32];
    const int tid = threadIdx.x;
    const int lane = tid & 63, w = tid >> 6;
    const int wm = w >> 1, wn = w & 1;
    const int ln15 = lane & 15, lg = lane >> 4;
    // XCD-aware swizzle (nwg % 8 == 0 for all our grids)
    const int nwg = gridDim.x * gridDim.y;
    const int lid = blockIdx.y * gridDim.x + blockIdx.x;
    const int swz = (lid & 7) * (nwg >> 3) + (lid >> 3);
    const int bm = swz / gridDim.x, bn = swz % gridDim.x;

    const f32x4 fzero = {0.f, 0.f, 0.f, 0.f};
    f32x4 acc[4][4];
#pragma unroll
    for (int m = 0; m < 4; m++)
#pragma unroll
        for (int n = 0; n < 4; n++) acc[m][n] = fzero;

    const __bf16* Ab = A + (size_t)(bm * 128) * K;
    const __bf16* Bb = Bt + (size_t)(bn * 128) * K;

    for (int k0 = 0; k0 < K; k0 += 32) {
#pragma unroll
        for (int i = 0; i < 2; i++) {
            int gid = i * 256 + tid;
            int row = gid >> 2, gc = gid & 3;
            gload16(Ab + (size_t)row * K + k0 + gc * 8, (char*)Al + gid * 16);
            gload16(Bb + (size_t)row * K + k0 + gc * 8, (char*)Bl + gid * 16);
        }
        __syncthreads();
        bf16x8 af[4], bfr[4];
#pragma unroll
        for (int m = 0; m < 4; m++)
            af[m] = *(const bf16x8*)&Al[(wm * 64 + m * 16 + ln15) * 32 + lg * 8];
#pragma unroll
        for (int n = 0; n < 4; n++)
            bfr[n] = *(const bf16x8*)&Bl[(wn * 64 + n * 16 + ln15) * 32 + lg * 8];
#pragma unroll
        for (int m = 0; m < 4; m++)
#pragma unroll
            for (int n = 0; n < 4; n++)
                acc[m][n] = __builtin_amdgcn_mfma_f32_16x16x32_bf16(af[m], bfr[n], acc[m][n], 0, 0, 0);
        __syncthreads();
    }

    // fused RoPE on q (cols<2048) and k (2048..2559); pairs are adjacent lanes (ln15 bit0)
    if (ROPE) {
#pragma unroll
        for (int n = 0; n < 4; n++) {
            const int col = bn * 128 + wn * 64 + n * 16 + ln15;
            if (col < 2560) {
                const int p = (col & 127) >> 1;
                const bool odd = (col & 1) != 0;
#pragma unroll
                for (int m = 0; m < 4; m++)
#pragma unroll
                    for (int r = 0; r < 4; r++) {
                        const int row = bm * 128 + wm * 64 + m * 16 + lg * 4 + r;
                        const int sp = row & 2047;
                        float c = fc[sp * 64 + p];
                        float sn = fs[sp * 64 + p];
                        float v = acc[m][n][r];
                        float v2 = __shfl_xor(v, 1);
                        acc[m][n][r] = odd ? (v2 * sn + v * c) : (v * c - v2 * sn);
                    }
            }
        }
    }

#pragma unroll
    for (int m = 0; m < 4; m++)
#pragma unroll
        for (int n = 0; n < 4; n++)
#pragma unroll
            for (int r = 0; r < 4; r++) {
                int row = bm * 128 + wm * 64 + m * 16 + lg * 4 + r;
                int col = bn * 128 + wn * 64 + n * 16 + ln15;
                C[(size_t)row * ldc + col] = (OT)acc[m][n][r];
            }
}

// ---------------- flash attention, causal, GQA rep=4 ----------------
// 512 blocks (balanced decode), 256 threads = 4 waves x 32 q-rows (QBLK=128), KVBLK=64.
// LDS 72 KB -> 2 blocks/CU. P half-buffer (16 rows) per wave; m=0/1 processed sequentially.
__global__ __launch_bounds__(256, 2) void attn_kernel(const __bf16* __restrict__ qkv,
                                                      const __bf16* __restrict__ vT,
                                                      __bf16* __restrict__ ctx) {
    __shared__ __align__(16) __bf16 Klds[2][64 * 128];   // [kv][d], granule g at g^(kv&7)
    __shared__ __align__(16) __bf16 VTlds[2][128 * 64];  // [d][kv], granule g at g^(d&7)
    __shared__ __align__(16) __bf16 Plds[4][16 * 64];    // per wave [16 q][64 kv], granule g at g^(q&7)

    const int tid = threadIdx.x, lane = tid & 63, w = tid >> 6;
    const int ln15 = lane & 15, lg = lane >> 4;
    // balanced decode: block i pairs with i+256 for ~constant per-CU work
    int i = blockIdx.x, qblk, hb;
    if (i < 256) { qblk = 15 - (i >> 5); hb = i & 31; }
    else { int j = i - 256; qblk = j >> 5; hb = j & 31; }
    const int h = hb >> 1, b = hb & 1;
    const int kvh = h >> 2;
    const int q0 = qblk * 128;
    const int qw0 = q0 + w * 32;
    const float c1 = 0.08838834764831845f * 1.4426950408889634f;  // scale * log2(e)

    const __bf16* qbase = qkv + (size_t)(b * 2048 + qw0 + ln15) * 3072 + h * 128;
    bf16x8 aq[2][4];
#pragma unroll
    for (int m = 0; m < 2; m++)
#pragma unroll
        for (int c = 0; c < 4; c++)
            aq[m][c] = *(const bf16x8*)(qbase + (size_t)m * 16 * 3072 + c * 32 + lg * 8);

    const __bf16* Kg = qkv + (size_t)(b * 2048) * 3072 + 2048 + kvh * 128;
    const __bf16* Vg = vT + (size_t)((b * 4 + kvh) * 128) * 2048;

    const f32x4 fzero = {0.f, 0.f, 0.f, 0.f};
    float m_run[2][4], l_run[2][4];
    f32x4 acc[2][8];
#pragma unroll
    for (int m = 0; m < 2; m++)
#pragma unroll
        for (int r = 0; r < 4; r++) { m_run[m][r] = -1e30f; l_run[m][r] = 0.f; }
#pragma unroll
    for (int m = 0; m < 2; m++)
#pragma unroll
        for (int dt = 0; dt < 8; dt++) acc[m][dt] = fzero;

    const int nt = 2 * qblk + 2;

#define STAGE(buf, t)                                                                     \
    do {                                                                                  \
        const int kb_ = (t) * 64;                                                         \
        _Pragma("unroll") for (int i2 = 0; i2 < 4; i2++) {                                \
            int gid = i2 * 256 + tid;                                                     \
            int kv = gid >> 4, sl = gid & 15;                                             \
            gload16(Kg + (size_t)(kb_ + kv) * 3072 + ((sl ^ (kv & 7)) * 8),               \
                    (char*)Klds[buf] + gid * 16);                                         \
        }                                                                                 \
        _Pragma("unroll") for (int i2 = 0; i2 < 4; i2++) {                                \
            int gid = i2 * 256 + tid;                                                     \
            int d = gid >> 3, sl = gid & 7;                                               \
            gload16(Vg + (size_t)d * 2048 + kb_ + ((sl ^ (d & 7)) * 8),                   \
                    (char*)VTlds[buf] + gid * 16);                                        \
        }                                                                                 \
    } while (0)

    STAGE(0, 0);
    __syncthreads();

    for (int t = 0; t < nt; t++) {
        const int cur = t & 1;
        const int kbase = t * 64;
        if (t + 1 < nt) STAGE(cur ^ 1, t + 1);  // prefetch next tile (overlaps compute)

        if (kbase <= qw0 + 31) {  // wave has unmasked rows in this tile
            // QK^T : S[32 q][64 kv]
            f32x4 st[2][4];
#pragma unroll
            for (int ct = 0; ct < 4; ct++) {
                int kv = ct * 16 + ln15;
                f32x4 s0 = fzero, s1 = fzero;
#pragma unroll
                for (int c = 0; c < 4; c++) {
                    int g = c * 4 + lg;
                    bf16x8 bk = *(const bf16x8*)&Klds[cur][kv * 128 + ((g ^ (kv & 7)) * 8)];
                    s0 = __builtin_amdgcn_mfma_f32_16x16x32_bf16(aq[0][c], bk, s0, 0, 0, 0);
                    s1 = __builtin_amdgcn_mfma_f32_16x16x32_bf16(aq[1][c], bk, s1, 0, 0, 0);
                }
                st[0][ct] = s0;
                st[1][ct] = s1;
            }
            // causal mask (only on diagonal tiles)
            if (kbase + 63 > qw0) {
#pragma unroll
                for (int m = 0; m < 2; m++)
#pragma unroll
                    for (int ct = 0; ct < 4; ct++) {
                        int kvi = kbase + ct * 16 + ln15;
#pragma unroll
                        for (int r = 0; r < 4; r++) {
                            int qi = qw0 + m * 16 + lg * 4 + r;
                            if (kvi > qi) st[m][ct][r] = -1e30f;
                        }
                    }
            }
            // per m-half: softmax + P write + PV (P half-buffer: 16 rows/wave)
#pragma unroll
            for (int m = 0; m < 2; m++) {
#pragma unroll
                for (int r = 0; r < 4; r++) {
                    float m0 = fmaxf(fmaxf(st[m][0][r], st[m][1][r]), fmaxf(st[m][2][r], st[m][3][r]));
#pragma unroll
                    for (int off = 1; off < 16; off <<= 1) m0 = fmaxf(m0, __shfl_xor(m0, off, 16));
                    float mn = fmaxf(m_run[m][r], m0);
                    float corr = exp2f((m_run[m][r] - mn) * c1);
                    m_run[m][r] = mn;
                    const int q = lg * 4 + r;
                    float sm = 0.f;
#pragma unroll
                    for (int ct = 0; ct < 4; ct++) {
                        float p = exp2f((st[m][ct][r] - mn) * c1);
                        sm += p;
                        int pg = ct * 2 + (ln15 >> 3);
                        Plds[w][q * 64 + ((pg ^ (q & 7)) * 8) + (ln15 & 7)] = (__bf16)p;
                    }
#pragma unroll
                    for (int off = 1; off < 16; off <<= 1) sm += __shfl_xor(sm, off, 16);
                    l_run[m][r] = l_run[m][r] * corr + sm;
#pragma unroll
                    for (int dt = 0; dt < 8; dt++) acc[m][dt][r] *= corr;
                }
#pragma unroll
                for (int s2 = 0; s2 < 2; s2++) {
                    const int kvg = s2 * 4 + lg;
                    bf16x8 pa = *(const bf16x8*)&Plds[w][ln15 * 64 + ((kvg ^ (ln15 & 7)) * 8)];
#pragma unroll
                    for (int dt = 0; dt < 8; dt++) {
                        int d = dt * 16 + ln15;
                        bf16x8 bv = *(const bf16x8*)&VTlds[cur][d * 64 + ((kvg ^ (d & 7)) * 8)];
                        acc[m][dt] = __builtin_amdgcn_mfma_f32_16x16x32_bf16(pa, bv, acc[m][dt], 0, 0, 0);
                    }
                }
            }
        }
        __syncthreads();
    }
#undef STAGE

    // epilogue: O / l -> ctx
    __bf16* crow = ctx + (size_t)(b * 2048 + qw0) * 2048 + h * 128;
#pragma unroll
    for (int m = 0; m < 2; m++)
#pragma unroll
        for (int dt = 0; dt < 8; dt++)
#pragma unroll
            for (int r = 0; r < 4; r++) {
                float v = acc[m][dt][r] / l_run[m][r];
                crow[(size_t)(m * 16 + lg * 4 + r) * 2048 + dt * 16 + ln15] = (__bf16)v;
            }
}

extern "C" void kernel_launch(void* const* d_in, const int* in_sizes, int n_in,
                              void* d_out, int out_size, void* d_ws, size_t ws_size,
                              hipStream_t stream) {
    const float* x = (const float*)d_in[0];
    const float* fc = (const float*)d_in[1];
    const float* fs = (const float*)d_in[2];
    const float* wq = (const float*)d_in[3];
    const float* wk = (const float*)d_in[4];
    const float* wv = (const float*)d_in[5];
    const float* wo = (const float*)d_in[6];
    float* out = (float*)d_out;

    char* ws = (char*)d_ws;
    __bf16* wT  = (__bf16*)ws;                        // [3072][2048] = wqT | wkT | wvT
    __bf16* woT = (__bf16*)(ws + 12582912);           // [2048][2048]
    __bf16* xb  = (__bf16*)(ws + 20971520);           // [4096][2048]  (dead after qkv GEMM)
    __bf16* qkv = (__bf16*)(ws + 37748736);           // [4096][3072] = q | k | v
    __bf16* ctx = (__bf16*)(ws + 62914560);           // [4096][2048]
    __bf16* vT  = xb;                                 // reuse xb region: [2][4][128][2048] = 4 MB

    // fused: x->bf16 + all 4 weight transposes
    prep_kernel<<<18432, 256, 0, stream>>>(x, wq, wk, wv, wo, (u16*)xb, (u16*)wT, (u16*)woT);

    // qkv projection with fused RoPE epilogue
    gemm_bt<__bf16, true><<<dim3(24, 32), 256, 0, stream>>>(xb, wT, qkv, 2048, 3072, fc, fs);

    // V -> vT (d-major) for gload16 staging in attention; safe to overwrite xb now
    transpose_v<<<dim3(16, 128), 256, 0, stream>>>((const u16*)qkv, (u16*)vT);

    attn_kernel<<<512, 256, 0, stream>>>(qkv, vT, ctx);

    gemm_bt<float, false><<<dim3(16, 32), 256, 0, stream>>>(ctx, woT, out, 2048, 2048, nullptr, nullptr);
}